// Round 1
// 7454.550 us; speedup vs baseline: 1.6456x; 1.6456x over previous
//
#include <hip/hip_runtime.h>
#include <math.h>

// CustomGRU B=64,S=512,F=512,H=1024. FP32 I/O, split-bf16 (hi+lo) MFMA compute.
// Round 6: attack per-step serialization (step was 57k cyc, all pipes <5% busy).
//  (1) Distributed grid barrier: 8 arrival counters on separate 128B lines
//      (32-way RMW contention instead of 256-way on one line), poll = single
//      asm block of 8 uncached loads + one waitcnt (one LLC round trip).
//  (2) h-phase fully pipelined: all 32 dwordx4 sc0sc1 loads issued up front
//      (8 base ptrs + offset: immediates), staged vmcnt(24/16/8/0) +
//      sched_barrier(0) before each MFMA cluster -> 1 LLC round trip not 4.
//  (3) x-side GEMM for step t+1 moved between arrive and poll (independent of
//      h) so it hides under barrier propagation.
//  (4) out/hf stores moved after arrive; pre-arrive vmcnt(0) drains only the
//      two h-shorts, not 256 scattered out lines.
//  (5) Cp re-padded (CPS 324 + intra-row pad): epilogue 4-way -> 2-way (free).

#define B_   64
#define S_   512
#define F_   512
#define H_   1024
#define KTOT 1536
#define NG   4096
#define NWG  256
#define NTHR 512
#define RS   1544             // padded LDS row stride (shorts)
#define CPS  324              // Cp tile stride (floats)
#define SMEM_BYTES (2 * 16 * RS * 2 + 32 * CPS * 4)   // 98816 + 41472 = 140288

typedef short short8 __attribute__((ext_vector_type(8)));
typedef float floatx4 __attribute__((ext_vector_type(4)));

__device__ __forceinline__ float bf2f(unsigned short u) {
    union { unsigned int i; float f; } v; v.i = ((unsigned int)u) << 16; return v.f;
}
__device__ __forceinline__ unsigned short f2bf(float f) {
    union { float f; unsigned int i; } v; v.f = f;
    unsigned int x = v.i;
    x += 0x7fffu + ((x >> 16) & 1u);
    return (unsigned short)(x >> 16);
}
__device__ __forceinline__ void split2(float v, unsigned short& hi, unsigned short& lo) {
    hi = f2bf(v);
    lo = f2bf(v - bf2f(hi));
}
__device__ __forceinline__ float tanh_fast(float a) {
    float e = __expf(-2.f * fabsf(a));      // in (0,1], no overflow
    float t = (1.f - e) / (1.f + e);
    return copysignf(t, a);
}

__global__ void pack_w(const float* __restrict__ Wih,
                       const float* __restrict__ Whh,
                       unsigned short* __restrict__ Whi,
                       unsigned short* __restrict__ Wlo) {
    int idx = blockIdx.x * 256 + threadIdx.x;   // < NG*KTOT
    int p = idx / KTOT;
    int k = idx - p * KTOT;
    int j = p >> 2, g = p & 3;
    float v = 0.f;
    if (g == 0)      v = (k < F_) ? Wih[k * 3072 + j]        : Whh[(k - F_) * 3072 + j];
    else if (g == 1) v = (k < F_) ? Wih[k * 3072 + 1024 + j] : Whh[(k - F_) * 3072 + 1024 + j];
    else if (g == 2) { if (k <  F_) v = Wih[k * 3072 + 2048 + j]; }
    else             { if (k >= F_) v = Whh[(k - F_) * 3072 + 2048 + j]; }
    unsigned short hi, lo; split2(v, hi, lo);
    Whi[idx] = hi; Wlo[idx] = lo;
}

__global__ void pack_x(const float* __restrict__ x,
                       unsigned short* __restrict__ xhi,
                       unsigned short* __restrict__ xlo) {
    int idx = blockIdx.x * 256 + threadIdx.x;   // < B_*S_*F_
    unsigned short hi, lo; split2(x[idx], hi, lo);
    xhi[idx] = hi; xlo[idx] = lo;
}

// x-side K step: plain cacheable (L1/L2) hi/lo loads
__device__ __forceinline__ void ks_step_x(floatx4* acc,
    const unsigned short* __restrict__ Ahi, const unsigned short* __restrict__ Alo,
    size_t aofs, const unsigned short* Bh_, const unsigned short* Bl_, int bofs)
{
    short8 bh = *(const short8*)&Bh_[bofs];
    short8 bl = *(const short8*)&Bl_[bofs];
    #pragma unroll
    for (int mt = 0; mt < 4; ++mt) {
        size_t o = aofs + (size_t)mt * ((size_t)16 * S_ * F_);
        short8 ah = *(const short8*)&Ahi[o];
        short8 al = *(const short8*)&Alo[o];
        acc[mt] = __builtin_amdgcn_mfma_f32_16x16x32_bf16(ah, bh, acc[mt], 0, 0, 0);
        acc[mt] = __builtin_amdgcn_mfma_f32_16x16x32_bf16(ah, bl, acc[mt], 0, 0, 0);
        acc[mt] = __builtin_amdgcn_mfma_f32_16x16x32_bf16(al, bh, acc[mt], 0, 0, 0);
    }
}

// Issue 8 device-scope loads (4 mt x hi/lo) for one 32-K slice, no wait.
#define LOADH(A, OFS) \
    asm volatile( \
        "global_load_dwordx4 %0, %[q0], off offset:" OFS " sc0 sc1\n\t" \
        "global_load_dwordx4 %1, %[q1], off offset:" OFS " sc0 sc1\n\t" \
        "global_load_dwordx4 %2, %[q2], off offset:" OFS " sc0 sc1\n\t" \
        "global_load_dwordx4 %3, %[q3], off offset:" OFS " sc0 sc1\n\t" \
        "global_load_dwordx4 %4, %[q4], off offset:" OFS " sc0 sc1\n\t" \
        "global_load_dwordx4 %5, %[q5], off offset:" OFS " sc0 sc1\n\t" \
        "global_load_dwordx4 %6, %[q6], off offset:" OFS " sc0 sc1\n\t" \
        "global_load_dwordx4 %7, %[q7], off offset:" OFS " sc0 sc1" \
        : "=&v"(A[0]), "=&v"(A[1]), "=&v"(A[2]), "=&v"(A[3]), \
          "=&v"(A[4]), "=&v"(A[5]), "=&v"(A[6]), "=&v"(A[7]) \
        : [q0]"v"(ph0), [q1]"v"(pl0), [q2]"v"(ph1), [q3]"v"(pl1), \
          [q4]"v"(ph2), [q5]"v"(pl2), [q6]"v"(ph3), [q7]"v"(pl3) \
        : "memory")

// Staged wait: only the h asm loads are in vmcnt at this point. sched_barrier
// pins the following MFMAs below the waitcnt (rule: compiler hoists reg-only
// MFMA past inline-asm waitcnt otherwise).
#define WAITVM(N) do { \
        asm volatile("s_waitcnt vmcnt(" #N ")" ::: "memory"); \
        __builtin_amdgcn_sched_barrier(0); \
    } while (0)

// A[] = {h0,l0,h1,l1,h2,l2,h3,l3}; per mt: ah*bh, ah*bl, al*bh
#define MFMAS(A, BH, BL) \
    acc[0] = __builtin_amdgcn_mfma_f32_16x16x32_bf16(A[0], BH, acc[0], 0, 0, 0); \
    acc[0] = __builtin_amdgcn_mfma_f32_16x16x32_bf16(A[0], BL, acc[0], 0, 0, 0); \
    acc[0] = __builtin_amdgcn_mfma_f32_16x16x32_bf16(A[1], BH, acc[0], 0, 0, 0); \
    acc[1] = __builtin_amdgcn_mfma_f32_16x16x32_bf16(A[2], BH, acc[1], 0, 0, 0); \
    acc[1] = __builtin_amdgcn_mfma_f32_16x16x32_bf16(A[2], BL, acc[1], 0, 0, 0); \
    acc[1] = __builtin_amdgcn_mfma_f32_16x16x32_bf16(A[3], BH, acc[1], 0, 0, 0); \
    acc[2] = __builtin_amdgcn_mfma_f32_16x16x32_bf16(A[4], BH, acc[2], 0, 0, 0); \
    acc[2] = __builtin_amdgcn_mfma_f32_16x16x32_bf16(A[4], BL, acc[2], 0, 0, 0); \
    acc[2] = __builtin_amdgcn_mfma_f32_16x16x32_bf16(A[5], BH, acc[2], 0, 0, 0); \
    acc[3] = __builtin_amdgcn_mfma_f32_16x16x32_bf16(A[6], BH, acc[3], 0, 0, 0); \
    acc[3] = __builtin_amdgcn_mfma_f32_16x16x32_bf16(A[6], BL, acc[3], 0, 0, 0); \
    acc[3] = __builtin_amdgcn_mfma_f32_16x16x32_bf16(A[7], BH, acc[3], 0, 0, 0)

__global__ __launch_bounds__(NTHR, 2) void gru_persist(
    const unsigned short* __restrict__ xhi,
    const unsigned short* __restrict__ xlo,
    const unsigned short* __restrict__ Whi,
    const unsigned short* __restrict__ Wlo,
    const float* __restrict__ bias,
    float* __restrict__ hf,
    unsigned short* hhi0, unsigned short* hlo0,
    unsigned short* hhi1, unsigned short* hlo1,
    float* __restrict__ out,
    float* __restrict__ hlast,
    unsigned* bar)
{
    extern __shared__ char smem[];
    unsigned short* Bh = (unsigned short*)smem;                 // 16 x RS shorts
    unsigned short* Bl = Bh + 16 * RS;
    float* Cp = (float*)(smem + 2 * 16 * RS * 2);               // 32 tiles x CPS f32

    const int tid = threadIdx.x;
    const int wg  = blockIdx.x;

    // ---- stage this wg's weight slice into LDS (once) ----
    for (int c = tid; c < 16 * 192; c += NTHR) {
        int row = c / 192, c8 = c - row * 192;
        size_t gofs = (size_t)(wg * 16 + row) * KTOT + c8 * 8;
        *(short8*)&Bh[row * RS + c8 * 8] = *(const short8*)&Whi[gofs];
        *(short8*)&Bl[row * RS + c8 * 8] = *(const short8*)&Wlo[gofs];
    }
    __syncthreads();

    const int lane = tid & 63;
    const int kw   = tid >> 6;                 // wave id 0..7
    const int l15  = lane & 15, quad = lane >> 4;
    // uniform split: wave kw covers x-K [kw*64, +64) and h-K [kw*128, +128)
    const int xk0   = kw * 64;
    const int hk0   = kw * 128;
    const int bofsx = l15 * RS + xk0 + quad * 8;
    const int bofsh = l15 * RS + 512 + hk0 + quad * 8;

    // epilogue constants (threads 0..255: one (batch, col) pair each)
    const int eb   = tid & 63;
    const int ejj  = (tid >> 6) & 3;
    const int ecol = wg * 4 + ejj;
    float bZ = 0.f, bR = 0.f, bE = 0.f;
    if (tid < 256) {
        bZ = bias[ecol];
        bR = bias[H_ + ecol];
        bE = bias[2 * H_ + ecol];
    }
    const int emt = eb >> 4, erow = eb & 15;
    const int err = erow & 3;
    const int cbase = 80 * (erow >> 2) + err;
    const int ehidx = eb * H_ + ecol;

    const size_t hrow = (size_t)l15 * H_ + quad * 8;
    const int cpw = lane * 4 + (lane >> 2) * 4;   // padded Cp write offset

    floatx4 z4v = {0.f, 0.f, 0.f, 0.f};

    // prologue: x-side contribution for t=0
    floatx4 accx[4] = {z4v, z4v, z4v, z4v};
    {
        const size_t xrow0 = ((size_t)l15 * S_) * F_ + quad * 8;
        #pragma unroll
        for (int ks = 0; ks < 2; ++ks)
            ks_step_x(accx, xhi, xlo, xrow0 + xk0 + ks * 32, Bh, Bl, bofsx + ks * 32);
    }

    for (int t = 0; t < S_; ++t) {
        const unsigned short* hih = (t & 1) ? hhi1 : hhi0;
        const unsigned short* hil = (t & 1) ? hlo1 : hlo0;
        unsigned short* hoh = (t & 1) ? hhi0 : hhi1;
        unsigned short* hol = (t & 1) ? hlo0 : hlo1;

        floatx4 acc[4] = {accx[0], accx[1], accx[2], accx[3]};

        // B fragments for all 4 h K-slices (LDS, lgkmcnt-tracked by compiler)
        short8 bhv[4], blv[4];
        #pragma unroll
        for (int ks = 0; ks < 4; ++ks) {
            bhv[ks] = *(const short8*)&Bh[bofsh + ks * 32];
            blv[ks] = *(const short8*)&Bl[bofsh + ks * 32];
        }

        const unsigned short* ph0 = hih + hrow + hk0;
        const unsigned short* pl0 = hil + hrow + hk0;
        const unsigned short* ph1 = ph0 + 16 * H_;
        const unsigned short* pl1 = pl0 + 16 * H_;
        const unsigned short* ph2 = ph0 + 32 * H_;
        const unsigned short* pl2 = pl0 + 32 * H_;
        const unsigned short* ph3 = ph0 + 48 * H_;
        const unsigned short* pl3 = pl0 + 48 * H_;

        // issue ALL 32 h loads, then consume with staged vmcnt
        short8 hv0[8], hv1[8], hv2[8], hv3[8];
        LOADH(hv0, "0");
        LOADH(hv1, "64");
        LOADH(hv2, "128");
        LOADH(hv3, "192");

        WAITVM(24); MFMAS(hv0, bhv[0], blv[0]);
        WAITVM(16); MFMAS(hv1, bhv[1], blv[1]);
        WAITVM(8);  MFMAS(hv2, bhv[2], blv[2]);
        WAITVM(0);  MFMAS(hv3, bhv[3], blv[3]);

        #pragma unroll
        for (int mt = 0; mt < 4; ++mt)
            *(floatx4*)&Cp[(kw * 4 + mt) * CPS + cpw] = acc[mt];
        __syncthreads();

        float hn = 0.f;
        if (tid < 256) {
            float g[4];
            #pragma unroll
            for (int gi = 0; gi < 4; ++gi) {
                const int c = ejj * 4 + gi;
                const int coff = cbase + 4 * c + 4 * (c >> 2);
                float s = 0.f;
                #pragma unroll
                for (int k2 = 0; k2 < 8; ++k2)
                    s += Cp[(k2 * 4 + emt) * CPS + coff];
                g[gi] = s;
            }
            float z   = 1.f / (1.f + __expf(-(g[0] + bZ)));
            float rr  = 1.f / (1.f + __expf(-(g[1] + bR)));
            float eta = tanh_fast(g[2] + bE + rr * tanh_fast(g[3]));
            float ho  = hf[ehidx];
            hn = z * ho + (1.f - z) * eta;
            unsigned short hi, lo; split2(hn, hi, lo);
            asm volatile("global_store_short %0, %1, off sc0 sc1"
                         :: "v"(&hoh[ehidx]), "v"((unsigned)hi) : "memory");
            asm volatile("global_store_short %0, %1, off sc0 sc1"
                         :: "v"(&hol[ehidx]), "v"((unsigned)lo) : "memory");
        }
        // drain ONLY the h stores (out/hf not issued yet), then arrive
        asm volatile("s_waitcnt vmcnt(0)" ::: "memory");
        __syncthreads();
        if (tid == 0)
            __hip_atomic_fetch_add(&bar[(wg & 7) * 32], 1u,
                                   __ATOMIC_RELAXED, __HIP_MEMORY_SCOPE_AGENT);

        // private stores: no cross-WG visibility requirement, off critical path
        if (tid < 256) {
            hf[ehidx] = hn;
            out[((size_t)eb * S_ + t) * H_ + ecol] = hn;
            if (t == S_ - 1) hlast[ehidx] = hn;
        }

        // x-side GEMM for t+1 overlaps with barrier propagation
        if (t + 1 < S_) {
            #pragma unroll
            for (int mt = 0; mt < 4; ++mt) accx[mt] = z4v;
            const size_t xrow = ((size_t)l15 * S_ + (t + 1)) * F_ + quad * 8;
            #pragma unroll
            for (int ks = 0; ks < 2; ++ks)
                ks_step_x(accx, xhi, xlo, xrow + xk0 + ks * 32, Bh, Bl, bofsx + ks * 32);
        }

        // distributed-counter poll: 8 lines, one round trip per poll
        if (tid == 0) {
            const unsigned target = (unsigned)(t + 1) * NWG;
            for (;;) {
                unsigned c0, c1, c2, c3, c4, c5, c6, c7;
                asm volatile(
                    "global_load_dword %0, %[a0], off sc0 sc1\n\t"
                    "global_load_dword %1, %[a1], off sc0 sc1\n\t"
                    "global_load_dword %2, %[a2], off sc0 sc1\n\t"
                    "global_load_dword %3, %[a3], off sc0 sc1\n\t"
                    "global_load_dword %4, %[a4], off sc0 sc1\n\t"
                    "global_load_dword %5, %[a5], off sc0 sc1\n\t"
                    "global_load_dword %6, %[a6], off sc0 sc1\n\t"
                    "global_load_dword %7, %[a7], off sc0 sc1\n\t"
                    "s_waitcnt vmcnt(0)"
                    : "=&v"(c0), "=&v"(c1), "=&v"(c2), "=&v"(c3),
                      "=&v"(c4), "=&v"(c5), "=&v"(c6), "=&v"(c7)
                    : [a0]"v"(bar),       [a1]"v"(bar + 32),
                      [a2]"v"(bar + 64),  [a3]"v"(bar + 96),
                      [a4]"v"(bar + 128), [a5]"v"(bar + 160),
                      [a6]"v"(bar + 192), [a7]"v"(bar + 224)
                    : "memory");
                if (c0 + c1 + c2 + c3 + c4 + c5 + c6 + c7 >= target) break;
                __builtin_amdgcn_s_sleep(1);
            }
        }
        __syncthreads();
    }
}

extern "C" void kernel_launch(void* const* d_in, const int* in_sizes, int n_in,
                              void* d_out, int out_size, void* d_ws, size_t ws_size,
                              hipStream_t stream) {
    const float* x    = (const float*)d_in[0];   // [B,S,F]
    const float* Wih  = (const float*)d_in[1];   // [F,3H]
    const float* Whh  = (const float*)d_in[2];   // [H,3H]
    const float* bias = (const float*)d_in[3];   // [3H]
    float* out = (float*)d_out;                  // [B,S,H] ++ [B,H]

    char* ws = (char*)d_ws;
    unsigned short* Whi = (unsigned short*)ws; ws += (size_t)NG * KTOT * 2;
    unsigned short* Wlo = (unsigned short*)ws; ws += (size_t)NG * KTOT * 2;
    unsigned short* xhi = (unsigned short*)ws; ws += (size_t)B_ * S_ * F_ * 2;
    unsigned short* xlo = (unsigned short*)ws; ws += (size_t)B_ * S_ * F_ * 2;
    float* hf = (float*)ws;                    ws += (size_t)B_ * H_ * 4;
    unsigned short* hhi0 = (unsigned short*)ws; ws += (size_t)B_ * H_ * 2;
    unsigned short* hlo0 = (unsigned short*)ws; ws += (size_t)B_ * H_ * 2;
    unsigned short* hhi1 = (unsigned short*)ws; ws += (size_t)B_ * H_ * 2;
    unsigned short* hlo1 = (unsigned short*)ws; ws += (size_t)B_ * H_ * 2;
    unsigned* bar = (unsigned*)ws;             ws += 1024;

    hipMemsetAsync(hf,   0, (size_t)B_ * H_ * 4, stream);
    hipMemsetAsync(hhi0, 0, (size_t)B_ * H_ * 2, stream);
    hipMemsetAsync(hlo0, 0, (size_t)B_ * H_ * 2, stream);
    hipMemsetAsync(bar,  0, 1024, stream);

    pack_w<<<(NG * KTOT) / 256, 256, 0, stream>>>(Wih, Whh, Whi, Wlo);
    pack_x<<<(B_ * S_ * F_) / 256, 256, 0, stream>>>(x, xhi, xlo);

    float* hlast = out + (size_t)B_ * S_ * H_;
    void* args[] = { &xhi, &xlo, &Whi, &Wlo, &bias, &hf,
                     &hhi0, &hlo0, &hhi1, &hlo1, &out, &hlast, &bar };
    hipLaunchCooperativeKernel((void*)gru_persist, dim3(NWG), dim3(NTHR),
                               args, SMEM_BYTES, stream);
}